// Round 11
// baseline (261.364 us; speedup 1.0000x reference)
//
#include <hip/hip_runtime.h>
#include <hip/hip_bf16.h>

#define LN_EPS 1e-5f
#define EPS64 (4096.0f * LN_EPS)
#define B_SZ 2048
#define LCH 150
#define HH 64
#define KK 9600
#define NSEG 16
#define NPAD 160
#define BB 4
#define RS 72

typedef __attribute__((ext_vector_type(8))) _Float16 f16x8;
typedef __attribute__((ext_vector_type(4))) float f32x4;

__device__ __forceinline__ float rcpf(float x) { return __builtin_amdgcn_rcpf(x); }
__device__ __forceinline__ float rsqf(float x) { return __builtin_amdgcn_rsqf(x); }

template<int CTRL>
__device__ __forceinline__ float dppadd16(float x) {
    int y = __builtin_amdgcn_update_dpp(0, __float_as_int(x), CTRL, 0xf, 0xf, true);
    return x + __int_as_float(y);
}
// sum within each 16-lane group (all lanes end with the sum)
__device__ __forceinline__ float red16(float x) {
    x = dppadd16<0xB1>(x);   // quad_perm 1,0,3,2
    x = dppadd16<0x4E>(x);   // quad_perm 2,3,0,1
    x = dppadd16<0x141>(x);  // row_half_mirror
    x = dppadd16<0x140>(x);  // row_mirror
    return x;
}

// -------- stats of W_ih: S = sum_n w_n w_n^T (16x16), cs = sum_n w_n --------
__global__ __launch_bounds__(256)
void wstat_kernel(const float* __restrict__ W_ih, float* __restrict__ Scs)
{
    const int tid = threadIdx.x;
    const int p = tid >> 4, q = tid & 15;
    float s = 0.f;
    for (int n = 0; n < 256; ++n)
        s += W_ih[n * 16 + p] * W_ih[n * 16 + q];
    Scs[p * 16 + q] = s;
    if (tid < 16) {
        float c = 0.f;
        for (int n = 0; n < 256; ++n) c += W_ih[n * 16 + tid];
        Scs[256 + tid] = c;
    }
}

// -------- prep: rep = eps*exp(0.5*logvar)+mu; balanced-64 fp16 limb A-frags
//          (slots: XH64[0:8], XH64[8:16], XL64[0:8], XL64[8:16]) + ih LN stats
//          stored pre-scaled for the 64-scaled accumulation: (mi*64, rsi/64) --------
__global__ __launch_bounds__(256)
void prep_kernel(const int* __restrict__ idx, const float* __restrict__ eps,
                 const float* __restrict__ mean_table, const float* __restrict__ var_table,
                 const float* __restrict__ Scs,
                 f16x8* __restrict__ repXf, float2* __restrict__ repS)
{
    const int gid = blockIdx.x * 256 + threadIdx.x;      // t*2048 + b
    const int t = gid >> 11, b = gid & 2047;
    const int id = idx[b * LCH + t];
    const float4* mp = (const float4*)(mean_table + (size_t)id * 16);
    const float4* vp = (const float4*)(var_table + (size_t)id * 16);
    const float4* ep = (const float4*)(eps + ((size_t)b * LCH + t) * 16);
    float x[16];
    #pragma unroll
    for (int q = 0; q < 4; ++q) {
        float4 m = mp[q], v = vp[q], e = ep[q];
        x[4*q+0] = e.x * __expf(0.5f * v.x) + m.x;
        x[4*q+1] = e.y * __expf(0.5f * v.y) + m.y;
        x[4*q+2] = e.z * __expf(0.5f * v.z) + m.z;
        x[4*q+3] = e.w * __expf(0.5f * v.w) + m.w;
    }
    float m1 = 0.f, qq = 0.f;
    #pragma unroll 4
    for (int p = 0; p < 16; ++p) {
        float sp = 0.f;
        #pragma unroll
        for (int q2 = 0; q2 < 16; ++q2) sp += Scs[p * 16 + q2] * x[q2];
        qq += x[p] * sp;
        m1 += Scs[256 + p] * x[p];
    }
    const float inv = 1.f / 256.f;
    m1 *= inv; qq *= inv;
    const float rs = rsqf(qq - m1 * m1 + LN_EPS);
    repS[gid] = make_float2(m1 * 64.f, rs * (1.f / 64.f));
    f16x8 H0, H1, L0, L1;
    #pragma unroll
    for (int f = 0; f < 8; ++f) {
        _Float16 h0_ = (_Float16)x[f];
        H0[f] = h0_ * (_Float16)64.f;
        L0[f] = (_Float16)((x[f] - (float)h0_) * 64.f);
        _Float16 h1_ = (_Float16)x[8 + f];
        H1[f] = h1_ * (_Float16)64.f;
        L1[f] = (_Float16)((x[8 + f] - (float)h1_) * 64.f);
    }
    f16x8* dst = repXf + (size_t)gid * 4;
    dst[0] = H0; dst[1] = H1; dst[2] = L0; dst[3] = L1;
}

// -------- W_out -> fp16, pre-transposed into MFMA-frag-contiguous layout --------
__global__ __launch_bounds__(256)
void wconv_kernel(const float* __restrict__ W, _Float16* __restrict__ Wt)
{
    const int gid = blockIdx.x * 256 + threadIdx.x;      // 300*10*64 = 192000
    const int ks = gid / 640;
    const int rem = gid - ks * 640;
    const int nt = rem >> 6;
    const int l = rem & 63;
    const int row = nt * 16 + (l & 15);
    const int k = ks * 32 + (l >> 4) * 8;
    f16x8 v;
    #pragma unroll
    for (int q = 0; q < 8; ++q) v[q] = (_Float16)0.f;
    if (row < 150) {
        const float4* p = (const float4*)(W + (size_t)row * KK + k);
        float4 a = p[0], b = p[1];
        v[0] = (_Float16)a.x; v[1] = (_Float16)a.y; v[2] = (_Float16)a.z; v[3] = (_Float16)a.w;
        v[4] = (_Float16)b.x; v[5] = (_Float16)b.y; v[6] = (_Float16)b.z; v[7] = (_Float16)b.w;
    }
    *(f16x8*)(Wt + (size_t)gid * 8) = v;
}

// -------- MFMA LSTM: BB=4, quad-mirrored A-rows; balanced LSC=64 limbs so ALL
// limb products land at scale 64 -> ONE acc set per LN group (8 f32x4 total).
// The 1/64 un-scale folds into the LN constants (EPS64, pre-scaled mi/rsi). --------
__global__ __launch_bounds__(256, 1)
void lstm_kernel(const float* __restrict__ h0, const float* __restrict__ c0,
                 const float* __restrict__ W_ih, const float* __restrict__ W_hh,
                 const float* __restrict__ g_ih, const float* __restrict__ bln_ih,
                 const float* __restrict__ g_hh, const float* __restrict__ bln_hh,
                 const float* __restrict__ g_c, const float* __restrict__ bln_c,
                 const f16x8* __restrict__ repXf, const float2* __restrict__ repS,
                 _Float16* __restrict__ hs_out)
{
    const int tid = threadIdx.x;
    const int m = tid & 15;
    const int g = (tid >> 4) & 3;
    const int w = tid >> 6;
    const int row0 = blockIdx.x * BB;
    const int j = w * 16 + m;
    const bool g01 = (g < 2);

    __shared__ _Float16 hH64[BB * RS];   // H * 64
    __shared__ _Float16 hHu[BB * RS];    // H (unscaled)
    __shared__ _Float16 hL64[BB * RS];   // (h - H) * 64
    __shared__ float2 st1[BB][4];        // [row][w] : 64-scaled (sum, sumsq) of hh
    __shared__ float2 st2[BB][4];        // [row][w] : (sum, sumsq) of c

    // ---- static weight fragments ----
    f16x8 WHf[4][2], WLf[4][2], Bi1[4], Bi2[4];
    float gihc[4], ghhc[4], bsc[4];
    #pragma unroll
    for (int tn = 0; tn < 4; ++tn) {
        const int n = tn * 64 + j;
        #pragma unroll
        for (int c = 0; c < 2; ++c) {
            const float* wp = W_hh + n * 64 + c * 32 + g * 8;
            #pragma unroll
            for (int q = 0; q < 8; ++q) {
                float v = wp[q];
                _Float16 h_ = (_Float16)v;
                WHf[tn][c][q] = h_;
                WLf[tn][c][q] = (_Float16)((v - (float)h_) * 64.f);
            }
        }
        const float* ip = W_ih + n * 16 + (g & 1) * 8;
        #pragma unroll
        for (int q = 0; q < 8; ++q) {
            float v = ip[q];
            _Float16 h_ = (_Float16)v;
            Bi1[tn][q] = h_;                                  // WH (all lane groups)
            Bi2[tn][q] = (_Float16)((v - (float)h_) * 64.f);  // WL64 (all lane groups)
        }
        gihc[tn] = g_ih[n];
        ghhc[tn] = g_hh[n];
        bsc[tn] = bln_ih[n] + bln_hh[n];
    }
    const float gcc = g_c[j], bcc = bln_c[j];
    const _Float16 a2s = g01 ? (_Float16)(1.0f / 64.f) : (_Float16)0.f;

    // ---- state init: c for own row (=g); h limbs (3 arrays) in LDS ----
    float c_reg = c0[(size_t)(row0 + g) * HH + j];
    {
        const int rr = tid >> 6, jj = tid & 63;      // 4 rows x 64 j
        float hv = h0[(size_t)(row0 + rr) * HH + jj];
        _Float16 Hh = (_Float16)hv;
        hHu[rr * RS + jj] = Hh;
        hH64[rr * RS + jj] = Hh * (_Float16)64.f;
        hL64[rr * RS + jj] = (_Float16)((hv - (float)Hh) * 64.f);
    }

    // x / stats prefetch (t=0); QUAD-mirrored row (m>>2); running pointers.
    // (t=150 prefetch reads past repXf/repS into adjacent ws regions: safe, unused.)
    const size_t rowx = (size_t)row0 + (m >> 2);
    const f16x8* axp = repXf + rowx * 4 + g;
    const float2* msp = repS + row0 + g;
    f16x8 AX = *axp;           axp += (size_t)2048 * 4;
    float2 mrs = *msp;         msp += 2048;
    _Float16* hp = hs_out + (size_t)(row0 + g) * KK + j;
    __syncthreads();

    const float INV256 = 1.f / 256.f, INV64 = 1.f / 64.f;

    for (int t = 0; t < LCH; ++t) {
        // ---- A-frags ----
        const f16x8 AH64_0 = *(const f16x8*)&hH64[(m >> 2) * RS + g * 8];
        const f16x8 AH64_1 = *(const f16x8*)&hH64[(m >> 2) * RS + 32 + g * 8];
        const f16x8 AHu_0  = *(const f16x8*)&hHu[(m >> 2) * RS + g * 8];
        const f16x8 AHu_1  = *(const f16x8*)&hHu[(m >> 2) * RS + 32 + g * 8];
        const f16x8 AL64_0 = *(const f16x8*)&hL64[(m >> 2) * RS + g * 8];
        const f16x8 AL64_1 = *(const f16x8*)&hL64[(m >> 2) * RS + 32 + g * 8];
        f16x8 A2;
        #pragma unroll
        for (int q = 0; q < 8; ++q) A2[q] = AX[q] * a2s;   // [XH|0] from [XH64|XL64]

        f32x4 ah[4], ai[4];
        #pragma unroll
        for (int tn = 0; tn < 4; ++tn) { ah[tn] = (f32x4)0.f; ai[tn] = (f32x4)0.f; }

        // ih: 64*(XH*WH + XL*WH) + 64*(XH*WL)  -> single acc
        #pragma unroll
        for (int tn = 0; tn < 4; ++tn) {
            ai[tn] = __builtin_amdgcn_mfma_f32_16x16x32_f16(AX, Bi1[tn], ai[tn], 0, 0, 0);
            ai[tn] = __builtin_amdgcn_mfma_f32_16x16x32_f16(A2, Bi2[tn], ai[tn], 0, 0, 0);
        }
        // hh: 64*(H*WH) + 64*(H*wl) + 64*(l*WH) -> single acc
        #pragma unroll
        for (int tn = 0; tn < 4; ++tn) {
            ah[tn] = __builtin_amdgcn_mfma_f32_16x16x32_f16(AH64_0, WHf[tn][0], ah[tn], 0, 0, 0);
            ah[tn] = __builtin_amdgcn_mfma_f32_16x16x32_f16(AH64_1, WHf[tn][1], ah[tn], 0, 0, 0);
            ah[tn] = __builtin_amdgcn_mfma_f32_16x16x32_f16(AHu_0, WLf[tn][0], ah[tn], 0, 0, 0);
            ah[tn] = __builtin_amdgcn_mfma_f32_16x16x32_f16(AHu_1, WLf[tn][1], ah[tn], 0, 0, 0);
            ah[tn] = __builtin_amdgcn_mfma_f32_16x16x32_f16(AL64_0, WHf[tn][0], ah[tn], 0, 0, 0);
            ah[tn] = __builtin_amdgcn_mfma_f32_16x16x32_f16(AL64_1, WHf[tn][1], ah[tn], 0, 0, 0);
        }

        // ---- prefetch next step (running pointers, no clamp) ----
        const f16x8 AXn = *axp;   axp += (size_t)2048 * 4;
        const float2 mrsn = *msp; msp += 2048;

        // ---- own row = element 0; values are 64-scaled (no combine needed) ----
        const float ohh0 = ah[0][0], ohh1 = ah[1][0], ohh2 = ah[2][0], ohh3 = ah[3][0];
        const float oih0 = ai[0][0], oih1 = ai[1][0], oih2 = ai[2][0], oih3 = ai[3][0];

        // ---- LN-256 hh stats (64-scaled) for own row ----
        {
            float s = red16((ohh0 + ohh1) + (ohh2 + ohh3));
            float qv = red16(ohh0*ohh0 + ohh1*ohh1 + ohh2*ohh2 + ohh3*ohh3);
            if (m == 0) st1[g][w] = make_float2(s, qv);
        }
        __syncthreads();   // B1

        float2 u0 = st1[g][0], u1 = st1[g][1], u2 = st1[g][2], u3 = st1[g][3];
        const float S1 = (u0.x + u1.x) + (u2.x + u3.x);
        const float Q1 = (u0.y + u1.y) + (u2.y + u3.y);
        const float mh = S1 * INV256;                       // 64*mean
        const float rsh = rsqf(Q1 * INV256 - mh * mh + EPS64);   // rs/64
        const float mi = mrs.x, rsi = mrs.y;                // pre-scaled in prep

        // ---- all 4 gates for own row (4 exp-chains) ----
        float act0, act1, act2, act3;
        {
            float ga = (ohh0 - mh) * rsh * ghhc[0] + (oih0 - mi) * rsi * gihc[0] + bsc[0];
            act0 = rcpf(1.f + __expf(-ga));
            float gb = (ohh1 - mh) * rsh * ghhc[1] + (oih1 - mi) * rsi * gihc[1] + bsc[1];
            act1 = rcpf(1.f + __expf(-gb));
            float gc2 = (ohh2 - mh) * rsh * ghhc[2] + (oih2 - mi) * rsi * gihc[2] + bsc[2];
            act2 = 2.f * rcpf(1.f + __expf(-2.f * gc2)) - 1.f;
            float gd = (ohh3 - mh) * rsh * ghhc[3] + (oih3 - mi) * rsi * gihc[3] + bsc[3];
            act3 = rcpf(1.f + __expf(-gd));
        }

        // ---- c update + LN-64 stats (true scale) ----
        c_reg = fmaf(act1, c_reg, act0 * act2);
        {
            float sc = red16(c_reg);
            float qc = red16(c_reg * c_reg);
            if (m == 0) st2[g][w] = make_float2(sc, qc);
        }
        __syncthreads();   // B2

        {
            float2 v0 = st2[g][0], v1 = st2[g][1], v2 = st2[g][2], v3 = st2[g][3];
            const float Sc = (v0.x + v1.x) + (v2.x + v3.x);
            const float Qc = (v0.y + v1.y) + (v2.y + v3.y);
            const float mc = Sc * INV64;
            const float rsc = rsqf(Qc * INV64 - mc * mc + LN_EPS);
            const float lnc = (c_reg - mc) * rsc * gcc + bcc;
            const float th = 2.f * rcpf(1.f + __expf(-2.f * lnc)) - 1.f;
            const float h = act3 * th;
            _Float16 Hh = (_Float16)h;
            hHu[g * RS + j] = Hh;
            hH64[g * RS + j] = Hh * (_Float16)64.f;
            hL64[g * RS + j] = (_Float16)((h - (float)Hh) * 64.f);
            hp[t * HH] = (_Float16)h;
        }
        __syncthreads();   // B3

        AX = AXn; mrs = mrsn;
    }
}

// -------- MFMA output GEMM: fp16 single-limb, 128 rows/block, frag-contiguous B --------
__global__ __launch_bounds__(256)
void gemm_kernel(const _Float16* __restrict__ hs,
                 const _Float16* __restrict__ Wt,
                 float* __restrict__ partial)
{
    const int mb = blockIdx.x;       // 0..15 (128 rows)
    const int seg = blockIdx.y;      // 0..15
    const int tid = threadIdx.x;
    const int l = tid & 63;
    const int w = tid >> 6;
    const int m = l & 15;
    const int lgrp = l >> 4;

    f32x4 acc[2][10];
    #pragma unroll
    for (int iA = 0; iA < 2; ++iA)
        #pragma unroll
        for (int nt = 0; nt < 10; ++nt) acc[iA][nt] = (f32x4)0.f;

    const int s0 = seg * 18 + (seg < 12 ? seg : 12);
    const int nst = 18 + (seg < 12 ? 1 : 0);

    const _Float16* ap0 = hs + (size_t)(mb * 128 + w * 16 + m) * KK + lgrp * 8;
    const _Float16* ap1 = ap0 + (size_t)64 * KK;

    for (int s = s0; s < s0 + nst; ++s) {
        const f16x8 A0 = *(const f16x8*)(ap0 + s * 32);
        const f16x8 A1 = *(const f16x8*)(ap1 + s * 32);
        const _Float16* bp = Wt + ((size_t)s * 640 + l) * 8;
        #pragma unroll
        for (int nt = 0; nt < 10; ++nt) {
            const f16x8 Bv = *(const f16x8*)(bp + nt * 512);
            acc[0][nt] = __builtin_amdgcn_mfma_f32_16x16x32_f16(A0, Bv, acc[0][nt], 0, 0, 0);
            acc[1][nt] = __builtin_amdgcn_mfma_f32_16x16x32_f16(A1, Bv, acc[1][nt], 0, 0, 0);
        }
    }
    #pragma unroll
    for (int iA = 0; iA < 2; ++iA) {
        float* po = partial + ((size_t)seg * B_SZ + mb * 128 + iA * 64 + w * 16 + lgrp * 4) * NPAD + m;
        #pragma unroll
        for (int nt = 0; nt < 10; ++nt)
            #pragma unroll
            for (int r = 0; r < 4; ++r)
                po[(size_t)r * NPAD + nt * 16] = acc[iA][nt][r];
    }
}

__global__ __launch_bounds__(256)
void reduce_kernel(const float* __restrict__ partial, const float* __restrict__ b_out,
                   float* __restrict__ out)
{
    const int i = blockIdx.x * 256 + threadIdx.x;   // row*150 + c
    const int row = i / 150;
    const int c = i - row * 150;
    float s = 0.f;
    #pragma unroll
    for (int g = 0; g < NSEG; ++g)
        s += partial[((size_t)g * B_SZ + row) * NPAD + c];
    out[i] = s + b_out[c];
}

extern "C" void kernel_launch(void* const* d_in, const int* in_sizes, int n_in,
                              void* d_out, int out_size, void* d_ws, size_t ws_size,
                              hipStream_t stream)
{
    const int*   idx        = (const int*)  d_in[0];
    const float* eps        = (const float*)d_in[1];
    const float* h0         = (const float*)d_in[2];
    const float* c0         = (const float*)d_in[3];
    const float* mean_table = (const float*)d_in[4];
    const float* var_table  = (const float*)d_in[5];
    const float* W_ih       = (const float*)d_in[6];
    const float* W_hh       = (const float*)d_in[7];
    const float* g_ih       = (const float*)d_in[8];
    const float* bln_ih     = (const float*)d_in[9];
    const float* g_hh       = (const float*)d_in[10];
    const float* bln_hh     = (const float*)d_in[11];
    const float* g_c        = (const float*)d_in[12];
    const float* bln_c      = (const float*)d_in[13];
    const float* W_out      = (const float*)d_in[14];
    const float* b_out      = (const float*)d_in[15];
    float* out = (float*)d_out;

    // ws layout (temporal aliasing):
    //  phase 1 (wstat/prep/lstm):  [0,19.66M)=repXf  [19.66,22.12M)=repS
    //  phase 2 (wconv/gemm/red):   [0,3.07M)=Wt fp16 [3.07,24.04M)=partial[16][2048][160]
    //  always: [24.05M, 63.37M)=hs fp16 ; [63.37M,+1088B)=Scs
    char* wsb = (char*)d_ws;
    const size_t repXf_b = (size_t)LCH * B_SZ * 64;        // 19,660,800
    const size_t repS_b  = (size_t)LCH * B_SZ * 8;         //  2,457,600
    const size_t wt_b    = (size_t)300 * 640 * 8 * 2;      //  3,072,000
    const size_t part_b  = (size_t)NSEG * B_SZ * NPAD * 4; // 20,971,520
    const size_t hs_off  = wt_b + part_b;                  // 24,043,520 > repXf+repS
    const size_t hs_b    = (size_t)B_SZ * KK * 2;          // 39,321,600

    f16x8* repXf = (f16x8*)wsb;
    float2* repS = (float2*)(wsb + repXf_b);
    _Float16* Wt = (_Float16*)wsb;
    float* partial = (float*)(wsb + wt_b);
    _Float16* hs = (_Float16*)(wsb + hs_off);
    float* Scs = (float*)(wsb + hs_off + hs_b);

    const size_t need = hs_off + hs_b + 272 * 4;
    if (ws_size < need) return;

    wstat_kernel<<<1, 256, 0, stream>>>(W_ih, Scs);
    prep_kernel<<<(B_SZ * LCH) / 256, 256, 0, stream>>>(idx, eps, mean_table, var_table,
                                                        Scs, repXf, repS);
    lstm_kernel<<<B_SZ / BB, 256, 0, stream>>>(h0, c0, W_ih, W_hh, g_ih, bln_ih,
                                               g_hh, bln_hh, g_c, bln_c,
                                               repXf, repS, hs);
    wconv_kernel<<<750, 256, 0, stream>>>(W_out, Wt);
    gemm_kernel<<<dim3(16, NSEG), 256, 0, stream>>>(hs, Wt, partial);
    reduce_kernel<<<(B_SZ * LCH) / 256, 256, 0, stream>>>(partial, b_out, out);
}

// Round 12
// 238.297 us; speedup vs baseline: 1.0968x; 1.0968x over previous
//
#include <hip/hip_runtime.h>
#include <hip/hip_bf16.h>

#define LN_EPS 1e-5f
#define B_SZ 2048
#define LCH 150
#define HH 64
#define KK 9600
#define NSEG 16
#define NPAD 160
#define BB 4
#define RS 72
#define LSC 4096.0f
#define ISC (1.0f/4096.0f)

typedef __attribute__((ext_vector_type(8))) _Float16 f16x8;
typedef __attribute__((ext_vector_type(4))) float f32x4;

__device__ __forceinline__ float rcpf(float x) { return __builtin_amdgcn_rcpf(x); }
__device__ __forceinline__ float rsqf(float x) { return __builtin_amdgcn_rsqf(x); }

template<int CTRL>
__device__ __forceinline__ float dppadd16(float x) {
    int y = __builtin_amdgcn_update_dpp(0, __float_as_int(x), CTRL, 0xf, 0xf, true);
    return x + __int_as_float(y);
}
// sum within each 16-lane group (all lanes end with the sum)
__device__ __forceinline__ float red16(float x) {
    x = dppadd16<0xB1>(x);   // quad_perm 1,0,3,2
    x = dppadd16<0x4E>(x);   // quad_perm 2,3,0,1
    x = dppadd16<0x141>(x);  // row_half_mirror
    x = dppadd16<0x140>(x);  // row_mirror
    return x;
}

// -------- stats of W_ih: S = sum_n w_n w_n^T (16x16), cs = sum_n w_n --------
__global__ __launch_bounds__(256)
void wstat_kernel(const float* __restrict__ W_ih, float* __restrict__ Scs)
{
    const int tid = threadIdx.x;
    const int p = tid >> 4, q = tid & 15;
    float s = 0.f;
    for (int n = 0; n < 256; ++n)
        s += W_ih[n * 16 + p] * W_ih[n * 16 + q];
    Scs[p * 16 + q] = s;
    if (tid < 16) {
        float c = 0.f;
        for (int n = 0; n < 256; ++n) c += W_ih[n * 16 + tid];
        Scs[256 + tid] = c;
    }
}

// -------- prep: rep = eps*exp(0.5*logvar)+mu; fp16 limb A-frags + ih LN stats --------
__global__ __launch_bounds__(256)
void prep_kernel(const int* __restrict__ idx, const float* __restrict__ eps,
                 const float* __restrict__ mean_table, const float* __restrict__ var_table,
                 const float* __restrict__ Scs,
                 f16x8* __restrict__ repXf, float2* __restrict__ repS)
{
    const int gid = blockIdx.x * 256 + threadIdx.x;      // t*2048 + b
    const int t = gid >> 11, b = gid & 2047;
    const int id = idx[b * LCH + t];
    const float4* mp = (const float4*)(mean_table + (size_t)id * 16);
    const float4* vp = (const float4*)(var_table + (size_t)id * 16);
    const float4* ep = (const float4*)(eps + ((size_t)b * LCH + t) * 16);
    float x[16];
    #pragma unroll
    for (int q = 0; q < 4; ++q) {
        float4 m = mp[q], v = vp[q], e = ep[q];
        x[4*q+0] = e.x * __expf(0.5f * v.x) + m.x;
        x[4*q+1] = e.y * __expf(0.5f * v.y) + m.y;
        x[4*q+2] = e.z * __expf(0.5f * v.z) + m.z;
        x[4*q+3] = e.w * __expf(0.5f * v.w) + m.w;
    }
    float m1 = 0.f, qq = 0.f;
    #pragma unroll 4
    for (int p = 0; p < 16; ++p) {
        float sp = 0.f;
        #pragma unroll
        for (int q2 = 0; q2 < 16; ++q2) sp += Scs[p * 16 + q2] * x[q2];
        qq += x[p] * sp;
        m1 += Scs[256 + p] * x[p];
    }
    const float inv = 1.f / 256.f;
    m1 *= inv; qq *= inv;
    const float rs = rsqf(qq - m1 * m1 + LN_EPS);
    repS[gid] = make_float2(m1, rs);
    f16x8 H0, H1, L0, L1;
    #pragma unroll
    for (int f = 0; f < 8; ++f) {
        _Float16 h0_ = (_Float16)x[f];
        H0[f] = h0_; L0[f] = (_Float16)((x[f] - (float)h0_) * LSC);
        _Float16 h1_ = (_Float16)x[8 + f];
        H1[f] = h1_; L1[f] = (_Float16)((x[8 + f] - (float)h1_) * LSC);
    }
    f16x8* dst = repXf + (size_t)gid * 4;
    dst[0] = H0; dst[1] = H1; dst[2] = L0; dst[3] = L1;
}

// -------- W_out -> fp16, pre-transposed into MFMA-frag-contiguous layout:
// Wt[kstep(300)][nt(10)][lane(64)][8], lane l=(m,lgrp): W[nt*16+m][kstep*32+lgrp*8+q] --------
__global__ __launch_bounds__(256)
void wconv_kernel(const float* __restrict__ W, _Float16* __restrict__ Wt)
{
    const int gid = blockIdx.x * 256 + threadIdx.x;      // 300*10*64 = 192000
    const int ks = gid / 640;
    const int rem = gid - ks * 640;
    const int nt = rem >> 6;
    const int l = rem & 63;
    const int row = nt * 16 + (l & 15);
    const int k = ks * 32 + (l >> 4) * 8;
    f16x8 v;
    #pragma unroll
    for (int q = 0; q < 8; ++q) v[q] = (_Float16)0.f;
    if (row < 150) {
        const float4* p = (const float4*)(W + (size_t)row * KK + k);
        float4 a = p[0], b = p[1];
        v[0] = (_Float16)a.x; v[1] = (_Float16)a.y; v[2] = (_Float16)a.z; v[3] = (_Float16)a.w;
        v[4] = (_Float16)b.x; v[5] = (_Float16)b.y; v[6] = (_Float16)b.z; v[7] = (_Float16)b.w;
    }
    *(f16x8*)(Wt + (size_t)gid * 8) = v;
}

// -------- MFMA LSTM (round-10 proven scheme): BB=4, QUAD-mirrored A-rows (m>>2)
// so C row q = batch row q>>2 -> element 0 of every acc is the thread's own row,
// zero cndmask selection. fp16 2-limb (LSC=4096). Running-pointer prefetch
// (numerics-neutral; t=150 over-read lands in allocated unused ws, discarded). --------
__global__ __launch_bounds__(256, 1)
void lstm_kernel(const float* __restrict__ h0, const float* __restrict__ c0,
                 const float* __restrict__ W_ih, const float* __restrict__ W_hh,
                 const float* __restrict__ g_ih, const float* __restrict__ bln_ih,
                 const float* __restrict__ g_hh, const float* __restrict__ bln_hh,
                 const float* __restrict__ g_c, const float* __restrict__ bln_c,
                 const f16x8* __restrict__ repXf, const float2* __restrict__ repS,
                 _Float16* __restrict__ hs_out)
{
    const int tid = threadIdx.x;
    const int m = tid & 15;
    const int g = (tid >> 4) & 3;
    const int w = tid >> 6;
    const int row0 = blockIdx.x * BB;
    const int j = w * 16 + m;

    __shared__ _Float16 hH[BB * RS];
    __shared__ _Float16 hL[BB * RS];
    __shared__ float2 st1[BB][4];   // [row][w] : (sum, sumsq) of hh gates
    __shared__ float2 st2[BB][4];   // [row][w] : (sum, sumsq) of c

    // ---- static weight fragments (all 4 tn: MFMA is wave-collective) ----
    f16x8 WHf[4][2], WLf[4][2], Bi1[4], Bi2[4];
    float gihc[4], ghhc[4], bsc[4];
    const bool g01 = (g < 2);
    #pragma unroll
    for (int tn = 0; tn < 4; ++tn) {
        const int n = tn * 64 + j;
        #pragma unroll
        for (int c = 0; c < 2; ++c) {
            const float* wp = W_hh + n * 64 + c * 32 + g * 8;
            #pragma unroll
            for (int q = 0; q < 8; ++q) {
                float v = wp[q];
                _Float16 h_ = (_Float16)v;
                WHf[tn][c][q] = h_;
                WLf[tn][c][q] = (_Float16)((v - (float)h_) * LSC);
            }
        }
        const float* ip = W_ih + n * 16 + (g & 1) * 8;
        #pragma unroll
        for (int q = 0; q < 8; ++q) {
            float v = ip[q];
            _Float16 h_ = (_Float16)v;
            _Float16 l_ = (_Float16)((v - (float)h_) * LSC);
            Bi1[tn][q] = g01 ? h_ : (_Float16)0.f;   // pass1: [WH | 0]
            Bi2[tn][q] = g01 ? l_ : h_;              // pass2: [WL'| WH]
        }
        gihc[tn] = g_ih[n];
        ghhc[tn] = g_hh[n];
        bsc[tn] = bln_ih[n] + bln_hh[n];
    }
    const float gcc = g_c[j], bcc = bln_c[j];

    // ---- state init: c for own row (=g); h limbs in LDS (4 rows) ----
    float c_reg = c0[(size_t)(row0 + g) * HH + j];
    {
        const int rr = tid >> 6, jj = tid & 63;      // 4 rows x 64 j
        float hv = h0[(size_t)(row0 + rr) * HH + jj];
        _Float16 Hh = (_Float16)hv;
        hH[rr * RS + jj] = Hh;
        hL[rr * RS + jj] = (_Float16)((hv - (float)Hh) * LSC);
    }

    // x / stats prefetch (t=0); QUAD-mirrored row (m>>2); running pointers
    const size_t rowx = (size_t)row0 + (m >> 2);
    const f16x8* axp = repXf + rowx * 4 + g;
    const float2* msp = repS + row0 + g;
    f16x8 AX = *axp;    axp += (size_t)2048 * 4;
    float2 mrs = *msp;  msp += 2048;
    _Float16* hp = hs_out + (size_t)(row0 + g) * KK + j;
    __syncthreads();

    const float INV256 = 1.f / 256.f, INV64 = 1.f / 64.f;

    for (int t = 0; t < LCH; ++t) {
        // ---- A-frags (quad-mirror: lanes 4u..4u+3 broadcast batch row u) ----
        const f16x8 AH0 = *(const f16x8*)&hH[(m >> 2) * RS + g * 8];
        const f16x8 AH1 = *(const f16x8*)&hH[(m >> 2) * RS + 32 + g * 8];
        const f16x8 AL0 = *(const f16x8*)&hL[(m >> 2) * RS + g * 8];
        const f16x8 AL1 = *(const f16x8*)&hL[(m >> 2) * RS + 32 + g * 8];

        f32x4 a1h[4], a2h[4], a1i[4], a2i[4];
        #pragma unroll
        for (int tn = 0; tn < 4; ++tn) {
            a1h[tn] = (f32x4)0.f; a2h[tn] = (f32x4)0.f;
            a1i[tn] = (f32x4)0.f; a2i[tn] = (f32x4)0.f;
        }
        #pragma unroll
        for (int tn = 0; tn < 4; ++tn) {
            a1h[tn] = __builtin_amdgcn_mfma_f32_16x16x32_f16(AH0, WHf[tn][0], a1h[tn], 0, 0, 0);
            a1h[tn] = __builtin_amdgcn_mfma_f32_16x16x32_f16(AH1, WHf[tn][1], a1h[tn], 0, 0, 0);
        }
        #pragma unroll
        for (int tn = 0; tn < 4; ++tn) {
            a2h[tn] = __builtin_amdgcn_mfma_f32_16x16x32_f16(AH0, WLf[tn][0], a2h[tn], 0, 0, 0);
            a2h[tn] = __builtin_amdgcn_mfma_f32_16x16x32_f16(AH1, WLf[tn][1], a2h[tn], 0, 0, 0);
            a2h[tn] = __builtin_amdgcn_mfma_f32_16x16x32_f16(AL0, WHf[tn][0], a2h[tn], 0, 0, 0);
            a2h[tn] = __builtin_amdgcn_mfma_f32_16x16x32_f16(AL1, WHf[tn][1], a2h[tn], 0, 0, 0);
        }
        #pragma unroll
        for (int tn = 0; tn < 4; ++tn) {
            a1i[tn] = __builtin_amdgcn_mfma_f32_16x16x32_f16(AX, Bi1[tn], a1i[tn], 0, 0, 0);
            a2i[tn] = __builtin_amdgcn_mfma_f32_16x16x32_f16(AX, Bi2[tn], a2i[tn], 0, 0, 0);
        }

        // ---- prefetch next step (running pointers, no clamp) ----
        const f16x8 AXn = *axp;   axp += (size_t)2048 * 4;
        const float2 mrsn = *msp; msp += 2048;

        // ---- own row = element 0 (all elements identical); limb combine ----
        float ohh[4], oih[4];
        #pragma unroll
        for (int tn = 0; tn < 4; ++tn) {
            ohh[tn] = fmaf(a2h[tn][0], ISC, a1h[tn][0]);
            oih[tn] = fmaf(a2i[tn][0], ISC, a1i[tn][0]);
        }

        // ---- LN-256 hh stats for own row ----
        {
            float s = red16((ohh[0] + ohh[1]) + (ohh[2] + ohh[3]));
            float qv = red16(ohh[0]*ohh[0] + ohh[1]*ohh[1] + ohh[2]*ohh[2] + ohh[3]*ohh[3]);
            if (m == 0) st1[g][w] = make_float2(s, qv);
        }
        __syncthreads();   // B1

        float2 u0 = st1[g][0], u1 = st1[g][1], u2 = st1[g][2], u3 = st1[g][3];
        const float S1 = (u0.x + u1.x) + (u2.x + u3.x);
        const float Q1 = (u0.y + u1.y) + (u2.y + u3.y);
        const float mh = S1 * INV256;
        const float rsh = rsqf(Q1 * INV256 - mh * mh + LN_EPS);
        const float mi = mrs.x, rsi = mrs.y;

        // ---- all 4 gates for own row (4 exp-chains) ----
        float act0, act1, act2, act3;
        {
            float ga = (ohh[0] - mh) * rsh * ghhc[0] + (oih[0] - mi) * rsi * gihc[0] + bsc[0];
            act0 = rcpf(1.f + __expf(-ga));
            float gb = (ohh[1] - mh) * rsh * ghhc[1] + (oih[1] - mi) * rsi * gihc[1] + bsc[1];
            act1 = rcpf(1.f + __expf(-gb));
            float gc2 = (ohh[2] - mh) * rsh * ghhc[2] + (oih[2] - mi) * rsi * gihc[2] + bsc[2];
            act2 = 2.f * rcpf(1.f + __expf(-2.f * gc2)) - 1.f;
            float gd = (ohh[3] - mh) * rsh * ghhc[3] + (oih[3] - mi) * rsi * gihc[3] + bsc[3];
            act3 = rcpf(1.f + __expf(-gd));
        }

        // ---- c update + LN-64 stats ----
        c_reg = fmaf(act1, c_reg, act0 * act2);
        {
            float sc = red16(c_reg);
            float qc = red16(c_reg * c_reg);
            if (m == 0) st2[g][w] = make_float2(sc, qc);
        }
        __syncthreads();   // B2

        {
            float2 v0 = st2[g][0], v1 = st2[g][1], v2 = st2[g][2], v3 = st2[g][3];
            const float Sc = (v0.x + v1.x) + (v2.x + v3.x);
            const float Qc = (v0.y + v1.y) + (v2.y + v3.y);
            const float mc = Sc * INV64;
            const float rsc = rsqf(Qc * INV64 - mc * mc + LN_EPS);
            const float lnc = (c_reg - mc) * rsc * gcc + bcc;
            const float th = 2.f * rcpf(1.f + __expf(-2.f * lnc)) - 1.f;
            const float h = act3 * th;
            _Float16 Hh = (_Float16)h;
            hH[g * RS + j] = Hh;
            hL[g * RS + j] = (_Float16)((h - (float)Hh) * LSC);
            hp[t * HH] = (_Float16)h;
        }
        __syncthreads();   // B3

        AX = AXn; mrs = mrsn;
    }
}

// -------- MFMA output GEMM: fp16 single-limb, 128 rows/block, frag-contiguous B.
// grid (16, 16) = 256 blocks; uneven K split: segs 0-11 get 19 k32-steps, 12-15 get 18. --------
__global__ __launch_bounds__(256)
void gemm_kernel(const _Float16* __restrict__ hs,
                 const _Float16* __restrict__ Wt,
                 float* __restrict__ partial)
{
    const int mb = blockIdx.x;       // 0..15 (128 rows)
    const int seg = blockIdx.y;      // 0..15
    const int tid = threadIdx.x;
    const int l = tid & 63;
    const int w = tid >> 6;
    const int m = l & 15;
    const int lgrp = l >> 4;

    f32x4 acc[2][10];
    #pragma unroll
    for (int iA = 0; iA < 2; ++iA)
        #pragma unroll
        for (int nt = 0; nt < 10; ++nt) acc[iA][nt] = (f32x4)0.f;

    const int s0 = seg * 18 + (seg < 12 ? seg : 12);
    const int nst = 18 + (seg < 12 ? 1 : 0);

    const _Float16* ap0 = hs + (size_t)(mb * 128 + w * 16 + m) * KK + lgrp * 8;
    const _Float16* ap1 = ap0 + (size_t)64 * KK;

    for (int s = s0; s < s0 + nst; ++s) {
        const f16x8 A0 = *(const f16x8*)(ap0 + s * 32);
        const f16x8 A1 = *(const f16x8*)(ap1 + s * 32);
        const _Float16* bp = Wt + ((size_t)s * 640 + l) * 8;
        #pragma unroll
        for (int nt = 0; nt < 10; ++nt) {
            const f16x8 Bv = *(const f16x8*)(bp + nt * 512);
            acc[0][nt] = __builtin_amdgcn_mfma_f32_16x16x32_f16(A0, Bv, acc[0][nt], 0, 0, 0);
            acc[1][nt] = __builtin_amdgcn_mfma_f32_16x16x32_f16(A1, Bv, acc[1][nt], 0, 0, 0);
        }
    }
    #pragma unroll
    for (int iA = 0; iA < 2; ++iA) {
        float* po = partial + ((size_t)seg * B_SZ + mb * 128 + iA * 64 + w * 16 + lgrp * 4) * NPAD + m;
        #pragma unroll
        for (int nt = 0; nt < 10; ++nt)
            #pragma unroll
            for (int r = 0; r < 4; ++r)
                po[(size_t)r * NPAD + nt * 16] = acc[iA][nt][r];
    }
}

__global__ __launch_bounds__(256)
void reduce_kernel(const float* __restrict__ partial, const float* __restrict__ b_out,
                   float* __restrict__ out)
{
    const int i = blockIdx.x * 256 + threadIdx.x;   // row*150 + c
    const int row = i / 150;
    const int c = i - row * 150;
    float s = 0.f;
    #pragma unroll
    for (int g = 0; g < NSEG; ++g)
        s += partial[((size_t)g * B_SZ + row) * NPAD + c];
    out[i] = s + b_out[c];
}

extern "C" void kernel_launch(void* const* d_in, const int* in_sizes, int n_in,
                              void* d_out, int out_size, void* d_ws, size_t ws_size,
                              hipStream_t stream)
{
    const int*   idx        = (const int*)  d_in[0];
    const float* eps        = (const float*)d_in[1];
    const float* h0         = (const float*)d_in[2];
    const float* c0         = (const float*)d_in[3];
    const float* mean_table = (const float*)d_in[4];
    const float* var_table  = (const float*)d_in[5];
    const float* W_ih       = (const float*)d_in[6];
    const float* W_hh       = (const float*)d_in[7];
    const float* g_ih       = (const float*)d_in[8];
    const float* bln_ih     = (const float*)d_in[9];
    const float* g_hh       = (const float*)d_in[10];
    const float* bln_hh     = (const float*)d_in[11];
    const float* g_c        = (const float*)d_in[12];
    const float* bln_c      = (const float*)d_in[13];
    const float* W_out      = (const float*)d_in[14];
    const float* b_out      = (const float*)d_in[15];
    float* out = (float*)d_out;

    // ws layout (temporal aliasing):
    //  phase 1 (wstat/prep/lstm):  [0,19.66M)=repXf  [19.66,22.12M)=repS
    //  phase 2 (wconv/gemm/red):   [0,3.07M)=Wt fp16 [3.07,24.04M)=partial[16][2048][160]
    //  always: [24.05M, 63.37M)=hs fp16 ; [63.37M,+1088B)=Scs
    char* wsb = (char*)d_ws;
    const size_t repXf_b = (size_t)LCH * B_SZ * 64;        // 19,660,800
    const size_t repS_b  = (size_t)LCH * B_SZ * 8;         //  2,457,600
    const size_t wt_b    = (size_t)300 * 640 * 8 * 2;      //  3,072,000
    const size_t part_b  = (size_t)NSEG * B_SZ * NPAD * 4; // 20,971,520
    const size_t hs_off  = wt_b + part_b;                  // 24,043,520 > repXf+repS
    const size_t hs_b    = (size_t)B_SZ * KK * 2;          // 39,321,600

    f16x8* repXf = (f16x8*)wsb;
    float2* repS = (float2*)(wsb + repXf_b);
    _Float16* Wt = (_Float16*)wsb;
    float* partial = (float*)(wsb + wt_b);
    _Float16* hs = (_Float16*)(wsb + hs_off);
    float* Scs = (float*)(wsb + hs_off + hs_b);

    const size_t need = hs_off + hs_b + 272 * 4;
    if (ws_size < need) return;

    wstat_kernel<<<1, 256, 0, stream>>>(W_ih, Scs);
    prep_kernel<<<(B_SZ * LCH) / 256, 256, 0, stream>>>(idx, eps, mean_table, var_table,
                                                        Scs, repXf, repS);
    lstm_kernel<<<B_SZ / BB, 256, 0, stream>>>(h0, c0, W_ih, W_hh, g_ih, bln_ih,
                                               g_hh, bln_hh, g_c, bln_c,
                                               repXf, repS, hs);
    wconv_kernel<<<750, 256, 0, stream>>>(W_out, Wt);
    gemm_kernel<<<dim3(16, NSEG), 256, 0, stream>>>(hs, Wt, partial);
    reduce_kernel<<<(B_SZ * LCH) / 256, 256, 0, stream>>>(partial, b_out, out);
}